// Round 3
// baseline (346.416 us; speedup 1.0000x reference)
//
#include <hip/hip_runtime.h>

#define BB 2
#define NN 2048
#define CC 1024
#define HH 16
#define HD 64

typedef __attribute__((ext_vector_type(8))) __bf16 bf16x8;
typedef __attribute__((ext_vector_type(4))) __bf16 bf16x4;
typedef __attribute__((ext_vector_type(4))) float f32x4;

__device__ inline bf16x8 cvt8(float4 a, float4 b) {
    bf16x8 r;
    r[0] = (__bf16)a.x; r[1] = (__bf16)a.y; r[2] = (__bf16)a.z; r[3] = (__bf16)a.w;
    r[4] = (__bf16)b.x; r[5] = (__bf16)b.y; r[6] = (__bf16)b.z; r[7] = (__bf16)b.w;
    return r;
}

// async global -> LDS, 16B per lane. dst must be wave-uniform base (HW adds lane*16).
__device__ inline void gload16(const void* g, void* l) {
    __builtin_amdgcn_global_load_lds(
        (const __attribute__((address_space(1))) unsigned int*)g,
        (__attribute__((address_space(3))) unsigned int*)l, 16, 0, 0);
}

// ---------------- 1. x -> bf16 + per-column partial sums ----------------
// grid 32 (b*16+rc), 256 threads; block handles 128 rows x 1024 cols.
__global__ __launch_bounds__(256) void k_prep(const float* __restrict__ x,
        __bf16* __restrict__ xbf, float* __restrict__ partial) {
    int blk = blockIdx.x, t = threadIdx.x;
    size_t base = (size_t)blk * 128 * CC + t * 4;
    const float* xp = x + base;
    __bf16* xo = xbf + base;
    float4 s = {0.f, 0.f, 0.f, 0.f};
    for (int i = 0; i < 128; ++i) {
        float4 v = *(const float4*)(xp + (size_t)i * CC);
        s.x += v.x; s.y += v.y; s.z += v.z; s.w += v.w;
        bf16x4 o;
        o[0] = (__bf16)v.x; o[1] = (__bf16)v.y; o[2] = (__bf16)v.z; o[3] = (__bf16)v.w;
        *(bf16x4*)(xo + (size_t)i * CC) = o;
    }
    *(float4*)(partial + (size_t)blk * CC + t * 4) = s;
}

// ---------------- 1b. fp32 -> bf16 weight convert ----------------
__global__ __launch_bounds__(256) void k_cvt(const float* __restrict__ src,
        __bf16* __restrict__ dst, int n8) {
    int i = blockIdx.x * 256 + threadIdx.x;
    if (i >= n8) return;
    const float4* sp = (const float4*)(src + (size_t)i * 8);
    *(bf16x8*)(dst + (size_t)i * 8) = cvt8(sp[0], sp[1]);
}

// ---------------- 2. gates * head-weight coef, scaled inv temps ----------------
__global__ __launch_bounds__(64) void k_coef(const float* __restrict__ partial,
        const float* __restrict__ gate_w, const float* __restrict__ gate_b,
        const float* __restrict__ dtemp, const float* __restrict__ hwts,
        const float* __restrict__ scale_p,
        float* __restrict__ coef, float* __restrict__ invt) {
    int p = blockIdx.x;
    int b = p >> 4, h = p & 15;
    int lane = threadIdx.x;
    float acc = 0.f;
    for (int c = lane; c < CC; c += 64) {
        float mv = 0.f;
        #pragma unroll
        for (int ch = 0; ch < 16; ++ch) mv += partial[(size_t)(b * 16 + ch) * CC + c];
        acc += (mv * (1.f / (float)NN)) * gate_w[h * CC + c];
    }
    #pragma unroll
    for (int m = 32; m; m >>= 1) acc += __shfl_xor(acc, m);
    if (lane == 0) {
        float g = 1.f / (1.f + __expf(-(acc + gate_b[h])));
        float mx = -1e30f;
        for (int i = 0; i < HH; ++i) mx = fmaxf(mx, hwts[i]);
        float s = 0.f;
        for (int i = 0; i < HH; ++i) s += __expf(hwts[i] - mx);
        float hw = __expf(hwts[h] - mx) / s;
        coef[p] = g * hw;
        if (b == 0) {
            float d = dtemp[h];
            float sp = (d > 20.f) ? d : log1pf(__expf(d));
            invt[h] = scale_p[0] / (sp * 1.0f /*BASE_TEMP*/);
        }
    }
}

// ---------------- 3/5. bf16 MFMA GEMM, m97-style, global_load_lds staging ----------
// C[M][O] = A[M][K] * Bw[O][K]^T. 256 thr = 4 waves (2x2), BK=32.
// EPI 0: scatter q (scaled by invt), k to [B,H,N,HD]; v TRANSPOSED to [B,H,HD,N].
// EPI 1: out[m*CC+o] = acc + bias[o] (f32)
template <int BM, int BN, int EPI>
__global__ __launch_bounds__(256) void k_gemm2(const __bf16* __restrict__ A,
        const __bf16* __restrict__ Bw, int K,
        __bf16* __restrict__ qo, __bf16* __restrict__ ko, __bf16* __restrict__ vto,
        const float* __restrict__ invt,
        float* __restrict__ outp, const float* __restrict__ bias) {
    constexpr int WM = BM / 2, WN = BN / 2, FM = WM / 16, FN = WN / 16;
    __shared__ __bf16 As[BM * 32];
    __shared__ __bf16 Bs[BN * 32];
    int t = threadIdx.x, lane = t & 63, w = t >> 6;
    int wr = w >> 1, wc = w & 1;
    int fr = lane & 15, kg = lane >> 4;
    int lr = lane >> 2, lc = lane & 3;
    int m0 = blockIdx.x * BM, o0 = blockIdx.y * BN;
    f32x4 acc[FM][FN] = {};
    for (int k0 = 0; k0 < K; k0 += 32) {
        __syncthreads();
        #pragma unroll
        for (int s = 0; s < BM / 64; ++s) {
            int r0 = w * (BM / 4) + s * 16;
            gload16(A + (size_t)(m0 + r0 + lr) * K + k0 + lc * 8, &As[r0 * 32]);
        }
        #pragma unroll
        for (int s = 0; s < BN / 64; ++s) {
            int r0 = w * (BN / 4) + s * 16;
            gload16(Bw + (size_t)(o0 + r0 + lr) * K + k0 + lc * 8, &Bs[r0 * 32]);
        }
        __syncthreads();
        bf16x8 av[FM], bv[FN];
        #pragma unroll
        for (int mi = 0; mi < FM; ++mi)
            av[mi] = *(const bf16x8*)&As[(wr * WM + mi * 16 + fr) * 32 + kg * 8];
        #pragma unroll
        for (int ni = 0; ni < FN; ++ni)
            bv[ni] = *(const bf16x8*)&Bs[(wc * WN + ni * 16 + fr) * 32 + kg * 8];
        #pragma unroll
        for (int mi = 0; mi < FM; ++mi)
            #pragma unroll
            for (int ni = 0; ni < FN; ++ni)
                acc[mi][ni] = __builtin_amdgcn_mfma_f32_16x16x32_bf16(av[mi], bv[ni],
                                                                      acc[mi][ni], 0, 0, 0);
    }
    #pragma unroll
    for (int mi = 0; mi < FM; ++mi)
        #pragma unroll
        for (int ni = 0; ni < FN; ++ni)
            #pragma unroll
            for (int reg = 0; reg < 4; ++reg) {
                int m = m0 + wr * WM + mi * 16 + kg * 4 + reg;
                int o = o0 + wc * WN + ni * 16 + fr;
                float val = acc[mi][ni][reg];
                if constexpr (EPI == 0) {
                    int part = o >> 10, f = o & 1023;
                    int h = f >> 6, d = f & 63;
                    int b = m >> 11, n = m & 2047;
                    if (part == 0)
                        qo[(((size_t)b * HH + h) * NN + n) * HD + d] = (__bf16)(val * invt[h]);
                    else if (part == 1)
                        ko[(((size_t)b * HH + h) * NN + n) * HD + d] = (__bf16)val;
                    else
                        vto[(((size_t)b * HH + h) * HD + d) * NN + n] = (__bf16)val;
                } else {
                    outp[(size_t)m * CC + o] = val + bias[o];
                }
            }
}

// ---------------- 4. flash attention, MFMA, dbuf gload_lds staging ----------------
// grid (N/64, H, B) x 256 (4 waves, 16 q-rows each). KV tile 64. One barrier/tile.
// K tile [key][d], V tile [d][key] (global already transposed); both LDS-linear with
// pre-swizzled source: 16B-slot swizzle  phys = logical ^ (row&7).
__global__ __launch_bounds__(256) void k_attn(const __bf16* __restrict__ qb,
        const __bf16* __restrict__ kb, const __bf16* __restrict__ vtb,
        __bf16* __restrict__ attno, const float* __restrict__ coef,
        const float* __restrict__ invt) {
    __shared__ __bf16 Ks[2][64][64];
    __shared__ __bf16 Vs[2][64][64];
    __shared__ __bf16 Ps[4][16][72];
    int t = threadIdx.x, w = t >> 6, lane = t & 63;
    int fr = lane & 15, kg = lane >> 4;
    int qt = blockIdx.x, h = blockIdx.y, b = blockIdx.z;
    int bh = b * HH + h;
    const __bf16* kbase = kb + (size_t)bh * NN * HD;
    const __bf16* vbase = vtb + (size_t)bh * HD * NN;
    float cf = coef[bh];

    int qrow = qt * 64 + w * 16 + fr;
    const __bf16* qp = qb + (size_t)bh * NN * HD + (size_t)qrow * HD;
    bf16x8 qf0 = *(const bf16x8*)(qp + kg * 8);
    bf16x8 qf1 = *(const bf16x8*)(qp + 32 + kg * 8);

    int srow = lane >> 3;            // 0..7 within 8-row shot
    int ssl  = (lane & 7) ^ srow;    // pre-swizzled source slot

    f32x4 o_acc[4] = {};
    float m_r[4], l_r[4];
    #pragma unroll
    for (int i = 0; i < 4; ++i) { m_r[i] = -INFINITY; l_r[i] = 0.f; }

    // prologue: stage tile 0 into buf 0
    #pragma unroll
    for (int s = 0; s < 2; ++s) {
        int r0 = w * 16 + s * 8;
        gload16(kbase + (size_t)(r0 + srow) * HD + ssl * 8, &Ks[0][r0][0]);
        gload16(vbase + (size_t)(r0 + srow) * NN + ssl * 8, &Vs[0][r0][0]);
    }
    int cur = 0;
    for (int kt = 0; kt < NN / 64; ++kt) {
        __syncthreads();   // vmcnt drained by barrier: buf[cur] ready
        if (kt + 1 < NN / 64) {
            #pragma unroll
            for (int s = 0; s < 2; ++s) {
                int r0 = w * 16 + s * 8;
                gload16(kbase + ((size_t)(kt + 1) * 64 + r0 + srow) * HD + ssl * 8,
                        &Ks[cur ^ 1][r0][0]);
                gload16(vbase + (size_t)(r0 + srow) * NN + (kt + 1) * 64 + ssl * 8,
                        &Vs[cur ^ 1][r0][0]);
            }
        }
        // S = Q K^T (scale folded into Q). C: row q = kg*4+reg, col key = j*16+fr
        f32x4 s_acc[4] = {};
        #pragma unroll
        for (int kk = 0; kk < 2; ++kk) {
            bf16x8 qf = kk ? qf1 : qf0;
            #pragma unroll
            for (int j = 0; j < 4; ++j) {
                int key = j * 16 + fr;
                bf16x8 kf = *(const bf16x8*)&Ks[cur][key][(((kk << 2) | kg) ^ (fr & 7)) * 8];
                s_acc[j] = __builtin_amdgcn_mfma_f32_16x16x32_bf16(qf, kf, s_acc[j], 0, 0, 0);
            }
        }
        // online softmax with defer-max (THR=8)
        #pragma unroll
        for (int reg = 0; reg < 4; ++reg) {
            float sv0 = s_acc[0][reg], sv1 = s_acc[1][reg];
            float sv2 = s_acc[2][reg], sv3 = s_acc[3][reg];
            float rm = fmaxf(fmaxf(sv0, sv1), fmaxf(sv2, sv3));
            rm = fmaxf(rm, __shfl_xor(rm, 1, 16));
            rm = fmaxf(rm, __shfl_xor(rm, 2, 16));
            rm = fmaxf(rm, __shfl_xor(rm, 4, 16));
            rm = fmaxf(rm, __shfl_xor(rm, 8, 16));
            float p0, p1, p2, p3, ts;
            if (__any(rm > m_r[reg] + 8.f)) {
                float mn = fmaxf(m_r[reg], rm);
                float a = __expf(m_r[reg] - mn);
                m_r[reg] = mn;
                p0 = __expf(sv0 - mn); p1 = __expf(sv1 - mn);
                p2 = __expf(sv2 - mn); p3 = __expf(sv3 - mn);
                ts = p0 + p1 + p2 + p3;
                ts += __shfl_xor(ts, 1, 16); ts += __shfl_xor(ts, 2, 16);
                ts += __shfl_xor(ts, 4, 16); ts += __shfl_xor(ts, 8, 16);
                l_r[reg] = l_r[reg] * a + ts;
                #pragma unroll
                for (int j2 = 0; j2 < 4; ++j2) o_acc[j2][reg] *= a;
            } else {
                float mn = m_r[reg];
                p0 = __expf(sv0 - mn); p1 = __expf(sv1 - mn);
                p2 = __expf(sv2 - mn); p3 = __expf(sv3 - mn);
                ts = p0 + p1 + p2 + p3;
                ts += __shfl_xor(ts, 1, 16); ts += __shfl_xor(ts, 2, 16);
                ts += __shfl_xor(ts, 4, 16); ts += __shfl_xor(ts, 8, 16);
                l_r[reg] += ts;
            }
            Ps[w][kg * 4 + reg][0 * 16 + fr] = (__bf16)p0;
            Ps[w][kg * 4 + reg][1 * 16 + fr] = (__bf16)p1;
            Ps[w][kg * 4 + reg][2 * 16 + fr] = (__bf16)p2;
            Ps[w][kg * 4 + reg][3 * 16 + fr] = (__bf16)p3;
        }
        // O += P V  (A = P[q][key], B = Vs[d][key])
        #pragma unroll
        for (int kk = 0; kk < 2; ++kk) {
            bf16x8 pf = *(const bf16x8*)&Ps[w][fr][kk * 32 + kg * 8];
            #pragma unroll
            for (int j2 = 0; j2 < 4; ++j2) {
                int d = j2 * 16 + fr;
                bf16x8 vf = *(const bf16x8*)&Vs[cur][d][(((kk << 2) | kg) ^ (fr & 7)) * 8];
                o_acc[j2] = __builtin_amdgcn_mfma_f32_16x16x32_bf16(pf, vf, o_acc[j2], 0, 0, 0);
            }
        }
        cur ^= 1;
    }
    #pragma unroll
    for (int reg = 0; reg < 4; ++reg) {
        int r = qt * 64 + w * 16 + kg * 4 + reg;
        float sc = cf / l_r[reg];
        __bf16* op = attno + ((size_t)b * NN + r) * (HH * HD) + h * HD;
        #pragma unroll
        for (int j2 = 0; j2 < 4; ++j2)
            op[j2 * 16 + fr] = (__bf16)(o_acc[j2][reg] * sc);
    }
}

extern "C" void kernel_launch(void* const* d_in, const int* in_sizes, int n_in,
                              void* d_out, int out_size, void* d_ws, size_t ws_size,
                              hipStream_t stream) {
    const float* x      = (const float*)d_in[0];
    const float* scale  = (const float*)d_in[1];
    const float* dtemp  = (const float*)d_in[2];
    const float* gate_w = (const float*)d_in[3];
    const float* gate_b = (const float*)d_in[4];
    const float* qkv_w  = (const float*)d_in[5];
    const float* out_w  = (const float*)d_in[6];
    const float* out_b  = (const float*)d_in[7];
    const float* hwts   = (const float*)d_in[8];

    char* wsb = (char*)d_ws;
    float*  partial = (float*)wsb;                      // 32*1024*4 = 128 KB
    float*  coefp   = (float*)(wsb + 131072);           // 32 f32
    float*  invtp   = (float*)(wsb + 131072 + 128);     // 16 f32
    char*   regA    = wsb + 131584;                     // 8 MB: xbf, later outw_bf
    char*   regB    = regA + (8u << 20);                // 8 MB: qkvw_bf, later attno
    const size_t HSZ = (size_t)BB * HH * NN * HD;       // 4M elems = 8 MB bf16
    __bf16* qbuf  = (__bf16*)(regB + (8u << 20));
    __bf16* kbuf  = qbuf + HSZ;
    __bf16* vtbuf = kbuf + HSZ;                         // [B,H,HD,N]
    __bf16* xbf     = (__bf16*)regA;                    // 8 MB (dead after QKV gemm)
    __bf16* outw_bf = (__bf16*)regA;                    // 2 MB (written after QKV gemm)
    __bf16* qkvw_bf = (__bf16*)regB;                    // 6 MB (dead after QKV gemm)
    __bf16* attno   = (__bf16*)regB;                    // 8 MB (written by attn)

    k_prep<<<32, 256, 0, stream>>>(x, xbf, partial);
    k_coef<<<32, 64, 0, stream>>>(partial, gate_w, gate_b, dtemp, hwts, scale, coefp, invtp);
    k_cvt<<<1536, 256, 0, stream>>>(qkv_w, qkvw_bf, 3 * HH * HD * CC / 8);
    k_gemm2<128, 128, 0><<<dim3(32, 24), 256, 0, stream>>>(xbf, qkvw_bf, CC,
            qbuf, kbuf, vtbuf, invtp, nullptr, nullptr);
    k_cvt<<<512, 256, 0, stream>>>(out_w, outw_bf, CC * HH * HD / 8);
    k_attn<<<dim3(NN / 64, HH, BB), 256, 0, stream>>>(qbuf, kbuf, vtbuf, attno, coefp, invtp);
    k_gemm2<64, 128, 1><<<dim3(64, 8), 256, 0, stream>>>(attno, outw_bf, HH * HD,
            nullptr, nullptr, nullptr, nullptr, (float*)d_out, out_b);
}

// Round 5
// 249.112 us; speedup vs baseline: 1.3906x; 1.3906x over previous
//
#include <hip/hip_runtime.h>

#define BB 2
#define NN 2048
#define CC 1024
#define HH 16
#define HD 64

typedef __attribute__((ext_vector_type(8))) __bf16 bf16x8;
typedef __attribute__((ext_vector_type(4))) __bf16 bf16x4;
typedef __attribute__((ext_vector_type(4))) float f32x4;

__device__ inline bf16x8 cvt8(float4 a, float4 b) {
    bf16x8 r;
    r[0] = (__bf16)a.x; r[1] = (__bf16)a.y; r[2] = (__bf16)a.z; r[3] = (__bf16)a.w;
    r[4] = (__bf16)b.x; r[5] = (__bf16)b.y; r[6] = (__bf16)b.z; r[7] = (__bf16)b.w;
    return r;
}

// async global -> LDS, 16B per lane. dst must be wave-uniform base (HW adds lane*16).
__device__ inline void gload16(const void* g, void* l) {
    __builtin_amdgcn_global_load_lds(
        (const __attribute__((address_space(1))) unsigned int*)g,
        (__attribute__((address_space(3))) unsigned int*)l, 16, 0, 0);
}

// ---------------- 1. x -> bf16 + per-column partial sums ----------------
// grid 256 (= b*128 + chunk), each block: 16 rows x 1024 cols.
__global__ __launch_bounds__(256) void k_prep(const float* __restrict__ x,
        __bf16* __restrict__ xbf, float* __restrict__ partial) {
    int blk = blockIdx.x, t = threadIdx.x;
    size_t base = (size_t)blk * 16 * CC + t * 4;
    const float* xp = x + base;
    __bf16* xo = xbf + base;
    float4 s = {0.f, 0.f, 0.f, 0.f};
    #pragma unroll 4
    for (int i = 0; i < 16; ++i) {
        float4 v = *(const float4*)(xp + (size_t)i * CC);
        s.x += v.x; s.y += v.y; s.z += v.z; s.w += v.w;
        bf16x4 o;
        o[0] = (__bf16)v.x; o[1] = (__bf16)v.y; o[2] = (__bf16)v.z; o[3] = (__bf16)v.w;
        *(bf16x4*)(xo + (size_t)i * CC) = o;
    }
    *(float4*)(partial + (size_t)blk * CC + t * 4) = s;
}

// ---------------- 1b. fp32 -> bf16 weight convert ----------------
__global__ __launch_bounds__(256) void k_cvt(const float* __restrict__ src,
        __bf16* __restrict__ dst, int n8) {
    int i = blockIdx.x * 256 + threadIdx.x;
    if (i >= n8) return;
    const float4* sp = (const float4*)(src + (size_t)i * 8);
    *(bf16x8*)(dst + (size_t)i * 8) = cvt8(sp[0], sp[1]);
}

// ---------------- 2. gates * head-weight coef, scaled inv temps ----------------
// 32 blocks (b*16+h) x 256 threads.
__global__ __launch_bounds__(256) void k_coef(const float* __restrict__ partial,
        const float* __restrict__ gate_w, const float* __restrict__ gate_b,
        const float* __restrict__ dtemp, const float* __restrict__ hwts,
        const float* __restrict__ scale_p,
        float* __restrict__ coef, float* __restrict__ invt) {
    __shared__ float red[4];
    int p = blockIdx.x;
    int b = p >> 4, h = p & 15;
    int t = threadIdx.x;
    float acc = 0.f;
    #pragma unroll
    for (int cc = 0; cc < 4; ++cc) {
        int c = cc * 256 + t;
        float mv = 0.f;
        for (int ch = 0; ch < 128; ++ch)
            mv += partial[(size_t)(b * 128 + ch) * CC + c];
        acc += (mv * (1.f / (float)NN)) * gate_w[h * CC + c];
    }
    #pragma unroll
    for (int m = 32; m; m >>= 1) acc += __shfl_xor(acc, m);
    if ((t & 63) == 0) red[t >> 6] = acc;
    __syncthreads();
    if (t == 0) {
        float tot = red[0] + red[1] + red[2] + red[3];
        float g = 1.f / (1.f + __expf(-(tot + gate_b[h])));
        float mx = -1e30f;
        for (int i = 0; i < HH; ++i) mx = fmaxf(mx, hwts[i]);
        float s = 0.f;
        for (int i = 0; i < HH; ++i) s += __expf(hwts[i] - mx);
        float hw = __expf(hwts[h] - mx) / s;
        coef[p] = g * hw;
        if (b == 0) {
            float d = dtemp[h];
            float sp = (d > 20.f) ? d : log1pf(__expf(d));
            invt[h] = scale_p[0] / (sp * 1.0f /*BASE_TEMP*/);
        }
    }
}

// ---------------- 3/5. bf16 MFMA GEMM, global_load_lds staging ----------
// C[M][O] = A[M][K] * Bw[O][K]^T. 256 thr = 4 waves (2x2), BK=32.
// EPI 0: scatter q (scaled by invt), k to [B,H,N,HD]; v TRANSPOSED to [B,H,HD,N].
// EPI 1: out[m*CC+o] = acc + bias[o] (f32)
template <int BM, int BN, int EPI>
__global__ __launch_bounds__(256) void k_gemm2(const __bf16* __restrict__ A,
        const __bf16* __restrict__ Bw, int K,
        __bf16* __restrict__ qo, __bf16* __restrict__ ko, __bf16* __restrict__ vto,
        const float* __restrict__ invt,
        float* __restrict__ outp, const float* __restrict__ bias) {
    constexpr int WM = BM / 2, WN = BN / 2, FM = WM / 16, FN = WN / 16;
    __shared__ __bf16 As[BM * 32];
    __shared__ __bf16 Bs[BN * 32];
    int t = threadIdx.x, lane = t & 63, w = t >> 6;
    int wr = w >> 1, wc = w & 1;
    int fr = lane & 15, kg = lane >> 4;
    int lr = lane >> 2, lc = lane & 3;
    int m0 = blockIdx.x * BM, o0 = blockIdx.y * BN;
    f32x4 acc[FM][FN] = {};
    for (int k0 = 0; k0 < K; k0 += 32) {
        __syncthreads();
        #pragma unroll
        for (int s = 0; s < BM / 64; ++s) {
            int r0 = w * (BM / 4) + s * 16;
            gload16(A + (size_t)(m0 + r0 + lr) * K + k0 + lc * 8, &As[r0 * 32]);
        }
        #pragma unroll
        for (int s = 0; s < BN / 64; ++s) {
            int r0 = w * (BN / 4) + s * 16;
            gload16(Bw + (size_t)(o0 + r0 + lr) * K + k0 + lc * 8, &Bs[r0 * 32]);
        }
        __syncthreads();
        bf16x8 av[FM], bv[FN];
        #pragma unroll
        for (int mi = 0; mi < FM; ++mi)
            av[mi] = *(const bf16x8*)&As[(wr * WM + mi * 16 + fr) * 32 + kg * 8];
        #pragma unroll
        for (int ni = 0; ni < FN; ++ni)
            bv[ni] = *(const bf16x8*)&Bs[(wc * WN + ni * 16 + fr) * 32 + kg * 8];
        #pragma unroll
        for (int mi = 0; mi < FM; ++mi)
            #pragma unroll
            for (int ni = 0; ni < FN; ++ni)
                acc[mi][ni] = __builtin_amdgcn_mfma_f32_16x16x32_bf16(av[mi], bv[ni],
                                                                      acc[mi][ni], 0, 0, 0);
    }
    #pragma unroll
    for (int mi = 0; mi < FM; ++mi)
        #pragma unroll
        for (int ni = 0; ni < FN; ++ni)
            #pragma unroll
            for (int reg = 0; reg < 4; ++reg) {
                int m = m0 + wr * WM + mi * 16 + kg * 4 + reg;
                int o = o0 + wc * WN + ni * 16 + fr;
                float val = acc[mi][ni][reg];
                if constexpr (EPI == 0) {
                    int part = o >> 10, f = o & 1023;
                    int h = f >> 6, d = f & 63;
                    int b = m >> 11, n = m & 2047;
                    if (part == 0)
                        qo[(((size_t)b * HH + h) * NN + n) * HD + d] = (__bf16)(val * invt[h]);
                    else if (part == 1)
                        ko[(((size_t)b * HH + h) * NN + n) * HD + d] = (__bf16)val;
                    else
                        vto[(((size_t)b * HH + h) * HD + d) * NN + n] = (__bf16)val;
                } else {
                    outp[(size_t)m * CC + o] = val + bias[o];
                }
            }
}

// ---------------- 4. flash attention, MFMA, swapped-QK softmax ----------------
// grid (N/128, H, B) x 512 (8 waves, 16 q-rows each). KV tile 64, dbuf, 1 barrier/tile.
// K tile [key][d], V tile [d][key] (global pre-transposed); LDS-linear with
// pre-swizzled source: 16B-slot phys = logical ^ (row&7).
__global__ __launch_bounds__(512, 4) void k_attn(const __bf16* __restrict__ qb,
        const __bf16* __restrict__ kb, const __bf16* __restrict__ vtb,
        __bf16* __restrict__ attno, const float* __restrict__ coef,
        const float* __restrict__ invt) {
    __shared__ __bf16 Ks[2][64][64];
    __shared__ __bf16 Vs[2][64][64];
    __shared__ __bf16 Ps[8][16][72];
    int t = threadIdx.x, w = t >> 6, lane = t & 63;
    int fr = lane & 15, kg = lane >> 4;
    int qt = blockIdx.x, h = blockIdx.y, b = blockIdx.z;
    int bh = b * HH + h;
    const __bf16* kbase = kb + (size_t)bh * NN * HD;
    const __bf16* vbase = vtb + (size_t)bh * HD * NN;
    float cf = coef[bh];

    // Q B-frags (q = fr within this wave's 16 rows), scale already folded in.
    int qrow = qt * 128 + w * 16 + fr;
    const __bf16* qp = qb + (size_t)bh * NN * HD + (size_t)qrow * HD;
    bf16x8 qf0 = *(const bf16x8*)(qp + kg * 8);
    bf16x8 qf1 = *(const bf16x8*)(qp + 32 + kg * 8);

    // staging: 512 threads cover 64 rows x 8 slots for K and V (1 shot each)
    int srow = lane >> 3;                 // 0..7; wave w covers rows w*8..w*8+7
    int ssl  = (lane & 7) ^ srow;         // pre-swizzled source slot
    int r0 = w * 8;
    int sl0 = (kg ^ (fr & 7)) * 8;        // swizzled LDS slot, kk=0
    int sl1 = ((4 | kg) ^ (fr & 7)) * 8;  // kk=1

    f32x4 o_acc[4] = {};
    float m_r = -INFINITY, l_r = 0.f;

    gload16(kbase + (size_t)(r0 + srow) * HD + ssl * 8, &Ks[0][r0][0]);
    gload16(vbase + (size_t)(r0 + srow) * NN + ssl * 8, &Vs[0][r0][0]);
    int cur = 0;
    for (int kt = 0; kt < NN / 64; ++kt) {
        __syncthreads();   // implicit vmcnt(0): buf[cur] ready
        if (kt + 1 < NN / 64) {
            gload16(kbase + ((size_t)(kt + 1) * 64 + r0 + srow) * HD + ssl * 8,
                    &Ks[cur ^ 1][r0][0]);
            gload16(vbase + (size_t)(r0 + srow) * NN + (kt + 1) * 64 + ssl * 8,
                    &Vs[cur ^ 1][r0][0]);
        }
        // S^T = K Q^T : A = K rows (j*16+fr), B = Q (col q = fr).
        // C: sT[j][reg] = S[key = j*16 + kg*4 + reg][q = fr]
        f32x4 sT[4] = {};
        #pragma unroll
        for (int kk = 0; kk < 2; ++kk) {
            bf16x8 qf = kk ? qf1 : qf0;
            int sl = kk ? sl1 : sl0;
            #pragma unroll
            for (int j = 0; j < 4; ++j) {
                bf16x8 kf = *(const bf16x8*)&Ks[cur][j * 16 + fr][sl];
                sT[j] = __builtin_amdgcn_mfma_f32_16x16x32_bf16(kf, qf, sT[j], 0, 0, 0);
            }
        }
        // row-max for q = fr: 16 local + 2 shfl (lanes sharing fr)
        float rm = fmaxf(fmaxf(fmaxf(sT[0][0], sT[0][1]), fmaxf(sT[0][2], sT[0][3])),
                         fmaxf(fmaxf(sT[1][0], sT[1][1]), fmaxf(sT[1][2], sT[1][3])));
        rm = fmaxf(rm, fmaxf(fmaxf(fmaxf(sT[2][0], sT[2][1]), fmaxf(sT[2][2], sT[2][3])),
                             fmaxf(fmaxf(sT[3][0], sT[3][1]), fmaxf(sT[3][2], sT[3][3]))));
        rm = fmaxf(rm, __shfl_xor(rm, 16));
        rm = fmaxf(rm, __shfl_xor(rm, 32));

        float p[4][4];
        float ts = 0.f;
        if (__any(rm > m_r + 8.f)) {          // rescale path (rare after warmup)
            float mn = fmaxf(m_r, rm);
            float a = __expf(m_r - mn);
            m_r = mn;
            #pragma unroll
            for (int j = 0; j < 4; ++j)
                #pragma unroll
                for (int reg = 0; reg < 4; ++reg) {
                    p[j][reg] = __expf(sT[j][reg] - mn);
                    ts += p[j][reg];
                }
            ts += __shfl_xor(ts, 16);
            ts += __shfl_xor(ts, 32);
            l_r = l_r * a + ts;
            #pragma unroll
            for (int reg = 0; reg < 4; ++reg) {
                float aq = __shfl(a, kg * 4 + reg, 16);  // a for q = kg*4+reg
                #pragma unroll
                for (int j2 = 0; j2 < 4; ++j2) o_acc[j2][reg] *= aq;
            }
        } else {                               // defer-max: keep old m, P <= e^8
            #pragma unroll
            for (int j = 0; j < 4; ++j)
                #pragma unroll
                for (int reg = 0; reg < 4; ++reg) {
                    p[j][reg] = __expf(sT[j][reg] - m_r);
                    ts += p[j][reg];
                }
            ts += __shfl_xor(ts, 16);
            ts += __shfl_xor(ts, 32);
            l_r += ts;
        }
        // P write: Ps[w][q=fr][key], 4 contiguous keys per b64
        #pragma unroll
        for (int j = 0; j < 4; ++j) {
            bf16x4 pk;
            pk[0] = (__bf16)p[j][0]; pk[1] = (__bf16)p[j][1];
            pk[2] = (__bf16)p[j][2]; pk[3] = (__bf16)p[j][3];
            *(bf16x4*)&Ps[w][fr][j * 16 + kg * 4] = pk;
        }
        // O += P V  (A = P[q][key], B = Vs[d][key])
        #pragma unroll
        for (int kk = 0; kk < 2; ++kk) {
            bf16x8 pf = *(const bf16x8*)&Ps[w][fr][kk * 32 + kg * 8];
            int sl = kk ? sl1 : sl0;
            #pragma unroll
            for (int j2 = 0; j2 < 4; ++j2) {
                bf16x8 vf = *(const bf16x8*)&Vs[cur][j2 * 16 + fr][sl];
                o_acc[j2] = __builtin_amdgcn_mfma_f32_16x16x32_bf16(pf, vf, o_acc[j2], 0, 0, 0);
            }
        }
        cur ^= 1;
    }
    // epilogue: per-q l via width-16 shfl, out = o * cf / l
    #pragma unroll
    for (int reg = 0; reg < 4; ++reg) {
        float lq = __shfl(l_r, kg * 4 + reg, 16);
        float sc = cf / lq;
        int r = qt * 128 + w * 16 + kg * 4 + reg;
        __bf16* op = attno + ((size_t)b * NN + r) * (HH * HD) + h * HD;
        #pragma unroll
        for (int j2 = 0; j2 < 4; ++j2)
            op[j2 * 16 + fr] = (__bf16)(o_acc[j2][reg] * sc);
    }
}

extern "C" void kernel_launch(void* const* d_in, const int* in_sizes, int n_in,
                              void* d_out, int out_size, void* d_ws, size_t ws_size,
                              hipStream_t stream) {
    const float* x      = (const float*)d_in[0];
    const float* scale  = (const float*)d_in[1];
    const float* dtemp  = (const float*)d_in[2];
    const float* gate_w = (const float*)d_in[3];
    const float* gate_b = (const float*)d_in[4];
    const float* qkv_w  = (const float*)d_in[5];
    const float* out_w  = (const float*)d_in[6];
    const float* out_b  = (const float*)d_in[7];
    const float* hwts   = (const float*)d_in[8];

    char* wsb = (char*)d_ws;
    float*  partial = (float*)wsb;                      // 256*1024*4 = 1 MB
    float*  coefp   = (float*)(wsb + (1u << 20));       // 32 f32
    float*  invtp   = (float*)(wsb + (1u << 20) + 128);
    char*   regA    = wsb + (1u << 20) + 512;           // 8 MB: xbf, later outw_bf
    char*   regB    = regA + (8u << 20);                // 8 MB: qkvw_bf, later attno
    const size_t HSZ = (size_t)BB * HH * NN * HD;       // 4M elems = 8 MB bf16
    __bf16* qbuf  = (__bf16*)(regB + (8u << 20));
    __bf16* kbuf  = qbuf + HSZ;
    __bf16* vtbuf = kbuf + HSZ;                         // [B,H,HD,N]
    __bf16* xbf     = (__bf16*)regA;
    __bf16* outw_bf = (__bf16*)regA;                    // written after QKV gemm
    __bf16* qkvw_bf = (__bf16*)regB;
    __bf16* attno   = (__bf16*)regB;                    // written by attn

    k_prep<<<256, 256, 0, stream>>>(x, xbf, partial);
    k_coef<<<32, 256, 0, stream>>>(partial, gate_w, gate_b, dtemp, hwts, scale, coefp, invtp);
    k_cvt<<<1536, 256, 0, stream>>>(qkv_w, qkvw_bf, 3 * HH * HD * CC / 8);
    k_gemm2<128, 128, 0><<<dim3(32, 24), 256, 0, stream>>>(xbf, qkvw_bf, CC,
            qbuf, kbuf, vtbuf, invtp, nullptr, nullptr);
    k_cvt<<<512, 256, 0, stream>>>(out_w, outw_bf, CC * HH * HD / 8);
    k_attn<<<dim3(NN / 128, HH, BB), 512, 0, stream>>>(qbuf, kbuf, vtbuf, attno, coefp, invtp);
    k_gemm2<64, 128, 1><<<dim3(64, 8), 256, 0, stream>>>(attno, outw_bf, HH * HD,
            nullptr, nullptr, nullptr, nullptr, (float*)d_out, out_b);
}

// Round 6
// 247.152 us; speedup vs baseline: 1.4016x; 1.0079x over previous
//
#include <hip/hip_runtime.h>

#define BB 2
#define NN 2048
#define CC 1024
#define HH 16
#define HD 64

typedef __attribute__((ext_vector_type(8))) __bf16 bf16x8;
typedef __attribute__((ext_vector_type(4))) __bf16 bf16x4;
typedef __attribute__((ext_vector_type(4))) float f32x4;

__device__ inline bf16x8 cvt8(float4 a, float4 b) {
    bf16x8 r;
    r[0] = (__bf16)a.x; r[1] = (__bf16)a.y; r[2] = (__bf16)a.z; r[3] = (__bf16)a.w;
    r[4] = (__bf16)b.x; r[5] = (__bf16)b.y; r[6] = (__bf16)b.z; r[7] = (__bf16)b.w;
    return r;
}

// async global -> LDS, 16B per lane. dst must be wave-uniform base (HW adds lane*16).
__device__ inline void gload16(const void* g, void* l) {
    __builtin_amdgcn_global_load_lds(
        (const __attribute__((address_space(1))) unsigned int*)g,
        (__attribute__((address_space(3))) unsigned int*)l, 16, 0, 0);
}

// ---------------- 1. fused: x->bf16 + col partial sums; qkv_w & out_w -> bf16 ----
// grid 2304: [0,256) prep, [256,1792) qkv_w cvt, [1792,2304) out_w cvt.
__global__ __launch_bounds__(256) void k_prep(const float* __restrict__ x,
        __bf16* __restrict__ xbf, float* __restrict__ partial,
        const float* __restrict__ qkv_w, __bf16* __restrict__ qkvw_bf,
        const float* __restrict__ out_w, __bf16* __restrict__ outw_bf) {
    int blk = blockIdx.x, t = threadIdx.x;
    if (blk < 256) {
        size_t base = (size_t)blk * 16 * CC + t * 4;
        const float* xp = x + base;
        __bf16* xo = xbf + base;
        float4 s = {0.f, 0.f, 0.f, 0.f};
        #pragma unroll 4
        for (int i = 0; i < 16; ++i) {
            float4 v = *(const float4*)(xp + (size_t)i * CC);
            s.x += v.x; s.y += v.y; s.z += v.z; s.w += v.w;
            bf16x4 o;
            o[0] = (__bf16)v.x; o[1] = (__bf16)v.y; o[2] = (__bf16)v.z; o[3] = (__bf16)v.w;
            *(bf16x4*)(xo + (size_t)i * CC) = o;
        }
        *(float4*)(partial + (size_t)blk * CC + t * 4) = s;
    } else if (blk < 1792) {
        size_t i = (size_t)(blk - 256) * 256 + t;
        const float4* sp = (const float4*)(qkv_w + i * 8);
        *(bf16x8*)(qkvw_bf + i * 8) = cvt8(sp[0], sp[1]);
    } else {
        size_t i = (size_t)(blk - 1792) * 256 + t;
        const float4* sp = (const float4*)(out_w + i * 8);
        *(bf16x8*)(outw_bf + i * 8) = cvt8(sp[0], sp[1]);
    }
}

// ---------------- 2. gates * head-weight coef, scaled inv temps ----------------
__global__ __launch_bounds__(256) void k_coef(const float* __restrict__ partial,
        const float* __restrict__ gate_w, const float* __restrict__ gate_b,
        const float* __restrict__ dtemp, const float* __restrict__ hwts,
        const float* __restrict__ scale_p,
        float* __restrict__ coef, float* __restrict__ invt) {
    __shared__ float red[4];
    int p = blockIdx.x;
    int b = p >> 4, h = p & 15;
    int t = threadIdx.x;
    float acc = 0.f;
    #pragma unroll
    for (int cc = 0; cc < 4; ++cc) {
        int c = cc * 256 + t;
        float mv = 0.f;
        for (int ch = 0; ch < 128; ++ch)
            mv += partial[(size_t)(b * 128 + ch) * CC + c];
        acc += (mv * (1.f / (float)NN)) * gate_w[h * CC + c];
    }
    #pragma unroll
    for (int m = 32; m; m >>= 1) acc += __shfl_xor(acc, m);
    if ((t & 63) == 0) red[t >> 6] = acc;
    __syncthreads();
    if (t == 0) {
        float tot = red[0] + red[1] + red[2] + red[3];
        float g = 1.f / (1.f + __expf(-(tot + gate_b[h])));
        float mx = -1e30f;
        for (int i = 0; i < HH; ++i) mx = fmaxf(mx, hwts[i]);
        float s = 0.f;
        for (int i = 0; i < HH; ++i) s += __expf(hwts[i] - mx);
        float hw = __expf(hwts[h] - mx) / s;
        coef[p] = g * hw;
        if (b == 0) {
            float d = dtemp[h];
            float sp = (d > 20.f) ? d : log1pf(__expf(d));
            invt[h] = scale_p[0] / (sp * 1.0f /*BASE_TEMP*/);
        }
    }
}

// ---------------- 3/5. bf16 MFMA GEMM, 2-phase dbuf pipeline + XCD supertiles ----
// C[M][O] = A[M][K] * Bw[O][K]^T. 256 thr = 4 waves (2x2), BK=32, dbuf LDS.
// 1D grid; bid -> (m-tile, o-tile) via 8-XCD supertile map (SX x SY tiles/supertile).
// EPI 0: q (scaled by invt), k -> [B,H,N,HD]; V-blocks (o0>=2048) use SWAPPED
//        mfma operands so the C-tile is transposed and V^T stores are coalesced.
// EPI 1: out[m*CC+o] = acc + bias[o]
template <int BM, int BN, int GX, int GY, int SX, int SY, int EPI>
__global__ __launch_bounds__(256, 3) void k_gemm2(const __bf16* __restrict__ A,
        const __bf16* __restrict__ Bw, int K,
        __bf16* __restrict__ qo, __bf16* __restrict__ ko, __bf16* __restrict__ vto,
        const float* __restrict__ invt,
        float* __restrict__ outp, const float* __restrict__ bias) {
    constexpr int WM = BM / 2, WN = BN / 2, FM = WM / 16, FN = WN / 16;
    constexpr int PER = SX * SY, NSTX = GX / SX;
    __shared__ __bf16 As[2][BM * 32];
    __shared__ __bf16 Bs[2][BN * 32];
    int t = threadIdx.x, lane = t & 63, w = t >> 6;
    int wr = w >> 1, wc = w & 1;
    int fr = lane & 15, kg = lane >> 4;
    int lr = lane >> 2, lc = lane & 3;
    int bid = blockIdx.x;
    int xcd = bid & 7, jj = bid >> 3;
    int st = xcd + 8 * (jj / PER);
    int inner = jj % PER;
    int m0 = ((st % NSTX) * SX + (inner % SX)) * BM;
    int o0 = ((st / NSTX) * SY + (inner / SX)) * BN;
    bool vblk = (EPI == 0) && (o0 >= 2 * HH * HD);

    f32x4 acc[FM][FN] = {};

    auto stage = [&](int k0, int buf) {
        #pragma unroll
        for (int s = 0; s < BM / 64; ++s) {
            int r0 = w * (BM / 4) + s * 16;
            gload16(A + (size_t)(m0 + r0 + lr) * K + k0 + lc * 8, &As[buf][r0 * 32]);
        }
        #pragma unroll
        for (int s = 0; s < BN / 64; ++s) {
            int r0 = w * (BN / 4) + s * 16;
            gload16(Bw + (size_t)(o0 + r0 + lr) * K + k0 + lc * 8, &Bs[buf][r0 * 32]);
        }
    };

    stage(0, 0);
    __syncthreads();
    int cur = 0;
    const int NK = K / 32;
    for (int ks = 0; ks < NK; ++ks) {
        if (ks + 1 < NK) stage((ks + 1) * 32, cur ^ 1);   // overlap with compute
        bf16x8 av[FM], bv[FN];
        #pragma unroll
        for (int mi = 0; mi < FM; ++mi)
            av[mi] = *(const bf16x8*)&As[cur][(wr * WM + mi * 16 + fr) * 32 + kg * 8];
        #pragma unroll
        for (int ni = 0; ni < FN; ++ni)
            bv[ni] = *(const bf16x8*)&Bs[cur][(wc * WN + ni * 16 + fr) * 32 + kg * 8];
        if (vblk) {
            #pragma unroll
            for (int mi = 0; mi < FM; ++mi)
                #pragma unroll
                for (int ni = 0; ni < FN; ++ni)
                    acc[mi][ni] = __builtin_amdgcn_mfma_f32_16x16x32_bf16(bv[ni], av[mi],
                                                                          acc[mi][ni], 0, 0, 0);
        } else {
            #pragma unroll
            for (int mi = 0; mi < FM; ++mi)
                #pragma unroll
                for (int ni = 0; ni < FN; ++ni)
                    acc[mi][ni] = __builtin_amdgcn_mfma_f32_16x16x32_bf16(av[mi], bv[ni],
                                                                          acc[mi][ni], 0, 0, 0);
        }
        __syncthreads();   // drains vmcnt: next buffer ready; all waves done with cur
        cur ^= 1;
    }

    if (vblk) {
        // transposed C: row-dim = o (kg*4+reg), col-dim = m (fr)
        #pragma unroll
        for (int mi = 0; mi < FM; ++mi)
            #pragma unroll
            for (int ni = 0; ni < FN; ++ni)
                #pragma unroll
                for (int reg = 0; reg < 4; ++reg) {
                    int o = o0 + wc * WN + ni * 16 + kg * 4 + reg;
                    int m = m0 + wr * WM + mi * 16 + fr;
                    int f = o - 2 * HH * HD;
                    int h = f >> 6, d = f & 63;
                    int b = m >> 11, n = m & 2047;
                    vto[(((size_t)b * HH + h) * HD + d) * NN + n] = (__bf16)acc[mi][ni][reg];
                }
    } else {
        #pragma unroll
        for (int mi = 0; mi < FM; ++mi)
            #pragma unroll
            for (int ni = 0; ni < FN; ++ni)
                #pragma unroll
                for (int reg = 0; reg < 4; ++reg) {
                    int m = m0 + wr * WM + mi * 16 + kg * 4 + reg;
                    int o = o0 + wc * WN + ni * 16 + fr;
                    float val = acc[mi][ni][reg];
                    if constexpr (EPI == 0) {
                        int part = o >> 10, f = o & 1023;   // part in {0,1}
                        int h = f >> 6, d = f & 63;
                        int b = m >> 11, n = m & 2047;
                        if (part == 0)
                            qo[(((size_t)b * HH + h) * NN + n) * HD + d] = (__bf16)(val * invt[h]);
                        else
                            ko[(((size_t)b * HH + h) * NN + n) * HD + d] = (__bf16)val;
                    } else {
                        outp[(size_t)m * CC + o] = val + bias[o];
                    }
                }
    }
}

// ---------------- 4. flash attention, MFMA, swapped-QK softmax ----------------
// 1D grid 512 x 512thr (8 waves, 16 q-rows each). XCD remap: all 16 q-tiles of a
// (b,h) pair land on one XCD (K/V stay L2-resident). KV tile 64, dbuf,
// 1 barrier/tile. K [key][d], V [d][key] (pre-transposed); 16B-slot XOR swizzle.
__global__ __launch_bounds__(512, 4) void k_attn(const __bf16* __restrict__ qb,
        const __bf16* __restrict__ kb, const __bf16* __restrict__ vtb,
        __bf16* __restrict__ attno, const float* __restrict__ coef,
        const float* __restrict__ invt) {
    __shared__ __bf16 Ks[2][64][64];
    __shared__ __bf16 Vs[2][64][64];
    __shared__ __bf16 Ps[8][16][64];     // XOR-swizzled 16B slots
    int t = threadIdx.x, w = t >> 6, lane = t & 63;
    int fr = lane & 15, kg = lane >> 4;
    int bid = blockIdx.x;
    int xcd = bid & 7, j0 = bid >> 3;
    int qt = j0 & 15;
    int bh = xcd * 4 + (j0 >> 4);
    int h = bh & 15, b = bh >> 4;
    const __bf16* kbase = kb + (size_t)bh * NN * HD;
    const __bf16* vbase = vtb + (size_t)bh * HD * NN;
    float cf = coef[bh];

    // Q B-frags (q = fr within this wave's 16 rows), scale folded in.
    int qrow = qt * 128 + w * 16 + fr;
    const __bf16* qp = qb + (size_t)bh * NN * HD + (size_t)qrow * HD;
    bf16x8 qf0 = *(const bf16x8*)(qp + kg * 8);
    bf16x8 qf1 = *(const bf16x8*)(qp + 32 + kg * 8);

    int srow = lane >> 3;                 // 0..7; wave w covers rows w*8..w*8+7
    int ssl  = (lane & 7) ^ srow;         // pre-swizzled source slot
    int r0 = w * 8;
    int sl0 = (kg ^ (fr & 7)) * 8;        // swizzled K/V LDS slot, kk=0
    int sl1 = ((4 | kg) ^ (fr & 7)) * 8;  // kk=1
    char* pr = (char*)&Ps[w][fr][0];      // 128B row

    f32x4 o_acc[4] = {};
    float m_r = -INFINITY, l_r = 0.f;     // l_r is lane-partial (kg-split)

    gload16(kbase + (size_t)(r0 + srow) * HD + ssl * 8, &Ks[0][r0][0]);
    gload16(vbase + (size_t)(r0 + srow) * NN + ssl * 8, &Vs[0][r0][0]);
    int cur = 0;
    for (int kt = 0; kt < NN / 64; ++kt) {
        __syncthreads();   // implicit vmcnt(0): buf[cur] ready
        if (kt + 1 < NN / 64) {
            gload16(kbase + ((size_t)(kt + 1) * 64 + r0 + srow) * HD + ssl * 8,
                    &Ks[cur ^ 1][r0][0]);
            gload16(vbase + (size_t)(r0 + srow) * NN + (kt + 1) * 64 + ssl * 8,
                    &Vs[cur ^ 1][r0][0]);
        }
        // S^T = K Q^T : sT[j][reg] = S[key = j*16 + kg*4 + reg][q = fr]
        f32x4 sT[4] = {};
        #pragma unroll
        for (int kk = 0; kk < 2; ++kk) {
            bf16x8 qf = kk ? qf1 : qf0;
            int sl = kk ? sl1 : sl0;
            #pragma unroll
            for (int j = 0; j < 4; ++j) {
                bf16x8 kf = *(const bf16x8*)&Ks[cur][j * 16 + fr][sl];
                sT[j] = __builtin_amdgcn_mfma_f32_16x16x32_bf16(kf, qf, sT[j], 0, 0, 0);
            }
        }
        // row-max for q = fr: 16 local + 2 shfl
        float rm = fmaxf(fmaxf(fmaxf(sT[0][0], sT[0][1]), fmaxf(sT[0][2], sT[0][3])),
                         fmaxf(fmaxf(sT[1][0], sT[1][1]), fmaxf(sT[1][2], sT[1][3])));
        rm = fmaxf(rm, fmaxf(fmaxf(fmaxf(sT[2][0], sT[2][1]), fmaxf(sT[2][2], sT[2][3])),
                             fmaxf(fmaxf(sT[3][0], sT[3][1]), fmaxf(sT[3][2], sT[3][3]))));
        rm = fmaxf(rm, __shfl_xor(rm, 16));
        rm = fmaxf(rm, __shfl_xor(rm, 32));

        float p[4][4];
        float ts = 0.f;
        if (__any(rm > m_r + 8.f)) {          // rescale path (rare after warmup)
            float mn = fmaxf(m_r, rm);
            float a = __expf(m_r - mn);
            m_r = mn;
            #pragma unroll
            for (int j = 0; j < 4; ++j)
                #pragma unroll
                for (int reg = 0; reg < 4; ++reg) {
                    p[j][reg] = __expf(sT[j][reg] - mn);
                    ts += p[j][reg];
                }
            l_r = l_r * a + ts;               // a uniform across kg for this fr
            #pragma unroll
            for (int reg = 0; reg < 4; ++reg) {
                float aq = __shfl(a, kg * 4 + reg, 16);
                #pragma unroll
                for (int j2 = 0; j2 < 4; ++j2) o_acc[j2][reg] *= aq;
            }
        } else {                               // defer-max: keep old m, P <= e^8
            #pragma unroll
            for (int j = 0; j < 4; ++j)
                #pragma unroll
                for (int reg = 0; reg < 4; ++reg) {
                    p[j][reg] = __expf(sT[j][reg] - m_r);
                    ts += p[j][reg];
                }
            l_r += ts;
        }
        // P -> Ps[w][q=fr][key], XOR-swizzled 16B slots
        #pragma unroll
        for (int j = 0; j < 4; ++j) {
            bf16x4 pk;
            pk[0] = (__bf16)p[j][0]; pk[1] = (__bf16)p[j][1];
            pk[2] = (__bf16)p[j][2]; pk[3] = (__bf16)p[j][3];
            *(bf16x4*)(pr + ((((j << 1) | (kg >> 1)) ^ (fr & 7)) << 4) + ((kg & 1) << 3)) = pk;
        }
        // O += P V  (A = P[q][key], B = Vs[d][key])
        #pragma unroll
        for (int kk = 0; kk < 2; ++kk) {
            bf16x8 pf = *(const bf16x8*)(pr + ((((kk << 2) | kg) ^ (fr & 7)) << 4));
            int sl = kk ? sl1 : sl0;
            #pragma unroll
            for (int j2 = 0; j2 < 4; ++j2) {
                bf16x8 vf = *(const bf16x8*)&Vs[cur][j2 * 16 + fr][sl];
                o_acc[j2] = __builtin_amdgcn_mfma_f32_16x16x32_bf16(pf, vf, o_acc[j2], 0, 0, 0);
            }
        }
        cur ^= 1;
    }
    // epilogue: finish l reduction (across kg), then per-q scale
    float lf = l_r;
    lf += __shfl_xor(lf, 16);
    lf += __shfl_xor(lf, 32);
    #pragma unroll
    for (int reg = 0; reg < 4; ++reg) {
        float lq = __shfl(lf, kg * 4 + reg, 16);
        float sc = cf / lq;
        int r = qt * 128 + w * 16 + kg * 4 + reg;
        __bf16* op = attno + ((size_t)b * NN + r) * (HH * HD) + h * HD;
        #pragma unroll
        for (int j2 = 0; j2 < 4; ++j2)
            op[j2 * 16 + fr] = (__bf16)(o_acc[j2][reg] * sc);
    }
}

extern "C" void kernel_launch(void* const* d_in, const int* in_sizes, int n_in,
                              void* d_out, int out_size, void* d_ws, size_t ws_size,
                              hipStream_t stream) {
    const float* x      = (const float*)d_in[0];
    const float* scale  = (const float*)d_in[1];
    const float* dtemp  = (const float*)d_in[2];
    const float* gate_w = (const float*)d_in[3];
    const float* gate_b = (const float*)d_in[4];
    const float* qkv_w  = (const float*)d_in[5];
    const float* out_w  = (const float*)d_in[6];
    const float* out_b  = (const float*)d_in[7];
    const float* hwts   = (const float*)d_in[8];

    char* wsb = (char*)d_ws;
    float*  partial = (float*)wsb;                      // 256*1024*4 = 1 MB
    float*  coefp   = (float*)(wsb + (1u << 20));       // 32 f32
    float*  invtp   = (float*)(wsb + (1u << 20) + 128);
    char*   regA    = wsb + (1u << 20) + 512;           // 8 MB: xbf, later outw_bf
    char*   regB    = regA + (8u << 20);                // 8 MB: qkvw_bf, later attno
    const size_t HSZ = (size_t)BB * HH * NN * HD;       // 4M elems = 8 MB bf16
    __bf16* qbuf  = (__bf16*)(regB + (8u << 20));
    __bf16* kbuf  = qbuf + HSZ;
    __bf16* vtbuf = kbuf + HSZ;                         // [B,H,HD,N]
    __bf16* xbf     = (__bf16*)regA;
    __bf16* outw_bf = (__bf16*)(regA + (6u << 20));     // disjoint from xbf? xbf is 8MB
    // NOTE: xbf occupies all of regA (8 MB) and is read by the QKV GEMM, while
    // outw_bf is written by k_prep BEFORE that GEMM. Keep them disjoint:
    // place outw_bf after vtbuf instead.
    outw_bf = (__bf16*)((char*)vtbuf + HSZ * sizeof(__bf16));   // +2 MB
    __bf16* qkvw_bf = (__bf16*)regB;
    __bf16* attno   = (__bf16*)regB;                    // reuses qkvw_bf after QKV gemm

    k_prep<<<2304, 256, 0, stream>>>(x, xbf, partial, qkv_w, qkvw_bf, out_w, outw_bf);
    k_coef<<<32, 256, 0, stream>>>(partial, gate_w, gate_b, dtemp, hwts, scale, coefp, invtp);
    k_gemm2<128, 128, 32, 24, 8, 3, 0><<<768, 256, 0, stream>>>(xbf, qkvw_bf, CC,
            qbuf, kbuf, vtbuf, invtp, nullptr, nullptr);
    k_attn<<<512, 512, 0, stream>>>(qbuf, kbuf, vtbuf, attno, coefp, invtp);
    k_gemm2<64, 128, 64, 8, 8, 2, 1><<<512, 256, 0, stream>>>(attno, outw_bf, HH * HD,
            nullptr, nullptr, nullptr, nullptr, (float*)d_out, out_b);
}